// Round 9
// baseline (289361.230 us; speedup 1.0000x reference)
//
#include <hip/hip_runtime.h>
#include <hip/hip_bf16.h>

typedef unsigned short u16;
typedef unsigned int   u32;

#define S_   256
#define B_   512
#define I_   70
#define ROWS 4
#define NB   (B_ / ROWS)   // 128 blocks
#define NT   1024          // 16 waves

// ---- bf16 helpers ----
__device__ __forceinline__ float bflo(u32 u) {   // low half of packed pair
    return __uint_as_float(u << 16);
}
__device__ __forceinline__ float bfhi(u32 u) {   // high half of packed pair
    return __uint_as_float(u & 0xffff0000u);
}
__device__ __forceinline__ u16 f2bf_u(float f) {
    __hip_bfloat16 h = __float2bfloat16(f);
    u16 r;
    __builtin_memcpy(&r, &h, 2);
    return r;
}
__device__ __forceinline__ float sigmoidf_(float x) {
    x = fminf(fmaxf(x, -30.f), 30.f);
    return 1.f / (1.f + __expf(-x));
}
__device__ __forceinline__ float tanhf_(float x) {
    x = fminf(fmaxf(x, -15.f), 15.f);
    float e = __expf(2.f * x);
    return (e - 1.f) / (e + 1.f);
}

// ---- diagnostic sentinel ----
__global__ __launch_bounds__(256)
void k_sentinel(float* __restrict__ out, int n, float v) {
    int i = blockIdx.x * 256 + threadIdx.x;
    if (i < n) out[i] = v;
}

// ---- zero the pacing counters ----
__global__ __launch_bounds__(256)
void k_zero(u32* __restrict__ p, int n) {
    int i = blockIdx.x * 256 + threadIdx.x;
    if (i < n) p[i] = 0u;
}

// ---- pack f32 -> bf16 ----
__global__ __launch_bounds__(256)
void k_pack(const float* __restrict__ src, u16* __restrict__ dst, int n) {
    int i = blockIdx.x * 256 + threadIdx.x;
    if (i < n) dst[i] = f2bf_u(src[i]);
}

// ---- pack first 512 cols of Wcomb2 [512][1024] -> bf16 [512][512] ----
__global__ __launch_bounds__(256)
void k_pack_cb2(const float* __restrict__ src, u16* __restrict__ dst) {
    int i = blockIdx.x * 256 + threadIdx.x;   // 512*512
    int e = i >> 9, k = i & 511;
    dst[i] = f2bf_u(src[(size_t)e * 1024 + k]);
}

// ---- beff[e] = bcomb2[e] + sum_h Wcomb2[e][512+h]  (M==ones fold) ----
__global__ __launch_bounds__(256)
void k_beff(const float* __restrict__ Wcomb2, const float* __restrict__ bcomb2,
            float* __restrict__ beff) {
    int e = blockIdx.x * 256 + threadIdx.x;
    if (e >= 512) return;
    float s = bcomb2[e];
    const float* wp = Wcomb2 + (size_t)e * 1024 + 512;
    for (int k = 0; k < 512; k++) s += wp[k];
    beff[e] = s;
}

// ====== persistent batch-partitioned scan, mixed f32/bf16 weights ======
// f32:  Whh1, Whh2 (recurrent, error compounds), Wc22 (direct pre-output).
// bf16: Wih1, Wc21, Wcomb2[:, :512], Wih2 (LN-damped paths).
// Per-step atomic pacing barrier keeps the 128 blocks convoyed so all 16
// blocks/XCD read the same weight lines while they are L2-resident.
__global__ __launch_bounds__(NT, 1)
void k_scan_b(const float* __restrict__ X, const float* __restrict__ M,
              const float* __restrict__ mask,
              const float* __restrict__ Wi2h, const float* __restrict__ bi2h,
              const float* __restrict__ Wcomb1, const float* __restrict__ bcomb1,
              const u16* __restrict__ Wbih1, const float* __restrict__ Whh1,
              const float* __restrict__ bih1, const float* __restrict__ bhh1,
              const u16* __restrict__ Wbc21, const float* __restrict__ bc21,
              const float* __restrict__ lg1, const float* __restrict__ lb1,
              const u16* __restrict__ Wbcb2, const float* __restrict__ beff,
              const u16* __restrict__ Wbih2, const float* __restrict__ Whh2,
              const float* __restrict__ bih2, const float* __restrict__ bhh2,
              const float* __restrict__ Wc22, const float* __restrict__ bc22,
              const float* __restrict__ lg2, const float* __restrict__ lb2,
              const float* __restrict__ Wnn1, const float* __restrict__ bnn1,
              const float* __restrict__ g3, const float* __restrict__ b3v,
              const float* __restrict__ Wnn2, const float* __restrict__ bnn2,
              u32* __restrict__ ctr, float* __restrict__ out) {
    __shared__ float h1s[ROWS * 512];      // 8 KB
    __shared__ float h2s[ROWS * 512];      // 8 KB
    __shared__ float c2s[ROWS * 512];      // 8 KB
    __shared__ float gbuf[2048 * ROWS];    // 32 KB; ys aliases gbuf[0:2048)
    __shared__ float c1s[ROWS * 64];       // 1 KB
    __shared__ float xm[ROWS * 128];       // 2 KB; reused as head staging
    float* ys = gbuf;

    const int tid  = threadIdx.x;
    const int w    = tid >> 6;
    const int lane = tid & 63;
    const int og   = lane >> 4;
    const int kl   = lane & 15;
    const int row0 = blockIdx.x * ROWS;

    // ---- h0 init (both layers) ----
    for (int c = tid; c < ROWS * 512; c += NT) {
        int r = c >> 9, h = c & 511;
        const float* xp = X + (size_t)(row0 + r) * I_ + 64;
        const float* wp = Wi2h + h * 6;
        float s = bi2h[h];
        #pragma unroll
        for (int j = 0; j < 6; j++) s = fmaf(xp[j], wp[j], s);
        h1s[c] = s;
        h2s[c] = s;
    }
    __syncthreads();

    for (int t = 0; t < S_; t++) {
        // ---- pacing barrier: no data crosses blocks; alignment only ----
        if (tid == 0) {
            __hip_atomic_fetch_add(&ctr[t], 1u, __ATOMIC_RELAXED,
                                   __HIP_MEMORY_SCOPE_AGENT);
            while (__hip_atomic_load(&ctr[t], __ATOMIC_RELAXED,
                                     __HIP_MEMORY_SCOPE_AGENT) < (u32)NB)
                __builtin_amdgcn_s_sleep(8);
        }
        __syncthreads();

        const float* mrow = mask + (size_t)t * B_ + row0;

        // ===== P0: stage X/M rows -> xm =====
        for (int c = tid; c < ROWS * 128; c += NT) {
            int r = c >> 7, k = c & 127;
            size_t rg = (size_t)t * B_ + row0 + r;
            xm[c] = (k < 64) ? X[rg * I_ + k] : M[rg * I_ + (k - 64)];
        }
        __syncthreads();

        // ===== P1: comb1 (64 outs, k=128, f32 Wcomb1 from L2) -> c1s =====
        {
            const int o = w * 4 + og;
            float racc[ROWS] = {0.f, 0.f, 0.f, 0.f};
            const float* wr = Wcomb1 + o * 128;
            #pragma unroll
            for (int seg = 0; seg < 2; seg++) {
                const int k = seg * 64 + kl * 4;
                float4 wv = *(const float4*)(wr + k);
                #pragma unroll
                for (int r = 0; r < ROWS; r++) {
                    float4 xv = *(const float4*)(xm + r * 128 + k);
                    racc[r] = fmaf(wv.x, xv.x, racc[r]);
                    racc[r] = fmaf(wv.y, xv.y, racc[r]);
                    racc[r] = fmaf(wv.z, xv.z, racc[r]);
                    racc[r] = fmaf(wv.w, xv.w, racc[r]);
                }
            }
            #pragma unroll
            for (int r = 0; r < ROWS; r++) {
                #pragma unroll
                for (int m = 1; m < 16; m <<= 1) racc[r] += __shfl_xor(racc[r], m, 64);
            }
            if (kl == 0) {
                #pragma unroll
                for (int r = 0; r < ROWS; r++) c1s[r * 64 + o] = racc[r] + bcomb1[o];
            }
        }
        __syncthreads();

        // ===== P2: GRU1 dots -> gbuf  (Whh1 f32, Wih1 bf16) =====
        for (int i = 0; i < 24; i++) {
            const int o = i * 64 + w * 4 + og;
            float rH[ROWS] = {0.f, 0.f, 0.f, 0.f};
            float rI[ROWS] = {0.f, 0.f, 0.f, 0.f};
            const float* wh = Whh1 + (size_t)o * 512;
            #pragma unroll
            for (int seg = 0; seg < 4; seg++) {
                const int k = seg * 128 + kl * 8;
                float4 wa = *(const float4*)(wh + k);
                float4 wb = *(const float4*)(wh + k + 4);
                #pragma unroll
                for (int r = 0; r < ROWS; r++) {
                    float4 xa = *(const float4*)(h1s + r * 512 + k);
                    float4 xb = *(const float4*)(h1s + r * 512 + k + 4);
                    rH[r] = fmaf(wa.x, xa.x, rH[r]);
                    rH[r] = fmaf(wa.y, xa.y, rH[r]);
                    rH[r] = fmaf(wa.z, xa.z, rH[r]);
                    rH[r] = fmaf(wa.w, xa.w, rH[r]);
                    rH[r] = fmaf(wb.x, xb.x, rH[r]);
                    rH[r] = fmaf(wb.y, xb.y, rH[r]);
                    rH[r] = fmaf(wb.z, xb.z, rH[r]);
                    rH[r] = fmaf(wb.w, xb.w, rH[r]);
                }
            }
            {   // k=64 over c1s (bf16 weights)
                uint2 q = ((const uint2*)(Wbih1 + (size_t)o * 64))[kl];
                const int k = kl * 4;
                #pragma unroll
                for (int r = 0; r < ROWS; r++) {
                    float4 xa = *(const float4*)(c1s + r * 64 + k);
                    rI[r] = fmaf(bflo(q.x), xa.x, rI[r]);
                    rI[r] = fmaf(bfhi(q.x), xa.y, rI[r]);
                    rI[r] = fmaf(bflo(q.y), xa.z, rI[r]);
                    rI[r] = fmaf(bfhi(q.y), xa.w, rI[r]);
                }
            }
            #pragma unroll
            for (int r = 0; r < ROWS; r++) {
                #pragma unroll
                for (int m = 1; m < 16; m <<= 1) {
                    rH[r] += __shfl_xor(rH[r], m, 64);
                    rI[r] += __shfl_xor(rI[r], m, 64);
                }
            }
            if (kl == 0) {
                if (o < 1024) {
                    #pragma unroll
                    for (int r = 0; r < ROWS; r++) gbuf[o * ROWS + r] = rH[r] + rI[r];
                } else {
                    #pragma unroll
                    for (int r = 0; r < ROWS; r++) {
                        gbuf[o * ROWS + r] = rH[r];
                        gbuf[(512 + o) * ROWS + r] = rI[r];
                    }
                }
            }
        }
        __syncthreads();
        // ===== P3: gates1 -> h1s =====
        for (int c = tid; c < ROWS * 512; c += NT) {
            const int r = c & (ROWS - 1), h = c >> 2;
            const float m = mrow[r];
            const int cc = r * 512 + h;
            const float hold = h1s[cc];
            float xr = gbuf[h * ROWS + r] + bih1[h] + bhh1[h];
            float xz = gbuf[(512 + h) * ROWS + r] + bih1[512 + h] + bhh1[512 + h];
            float hn = gbuf[(1024 + h) * ROWS + r] + bhh1[1024 + h];
            float xn = gbuf[(1536 + h) * ROWS + r] + bih1[1024 + h];
            float rg = sigmoidf_(xr);
            float zg = sigmoidf_(xz);
            float ng = tanhf_(xn + rg * hn);
            h1s[cc] = ((1.f - zg) * ng + zg * hold) * m + hold * (1.f - m);
        }
        __syncthreads();
        // ===== P4: B1a out1 -> ys  (Wc21 bf16) =====
        for (int i = 0; i < 8; i++) {
            const int o = i * 64 + w * 4 + og;
            float racc[ROWS] = {0.f, 0.f, 0.f, 0.f};
            const u16* wr = Wbc21 + (size_t)o * 576;
            {   // cols 0..63 vs c1s
                uint2 q = ((const uint2*)wr)[kl];
                const int k = kl * 4;
                #pragma unroll
                for (int r = 0; r < ROWS; r++) {
                    float4 xa = *(const float4*)(c1s + r * 64 + k);
                    racc[r] = fmaf(bflo(q.x), xa.x, racc[r]);
                    racc[r] = fmaf(bfhi(q.x), xa.y, racc[r]);
                    racc[r] = fmaf(bflo(q.y), xa.z, racc[r]);
                    racc[r] = fmaf(bfhi(q.y), xa.w, racc[r]);
                }
            }
            const uint4* wq = (const uint4*)(wr + 64);
            #pragma unroll
            for (int seg = 0; seg < 4; seg++) {
                uint4 q = wq[seg * 16 + kl];
                const int k = seg * 128 + kl * 8;
                #pragma unroll
                for (int r = 0; r < ROWS; r++) {
                    float4 xa = *(const float4*)(h1s + r * 512 + k);
                    float4 xb = *(const float4*)(h1s + r * 512 + k + 4);
                    racc[r] = fmaf(bflo(q.x), xa.x, racc[r]);
                    racc[r] = fmaf(bfhi(q.x), xa.y, racc[r]);
                    racc[r] = fmaf(bflo(q.y), xa.z, racc[r]);
                    racc[r] = fmaf(bfhi(q.y), xa.w, racc[r]);
                    racc[r] = fmaf(bflo(q.z), xb.x, racc[r]);
                    racc[r] = fmaf(bfhi(q.z), xb.y, racc[r]);
                    racc[r] = fmaf(bflo(q.w), xb.z, racc[r]);
                    racc[r] = fmaf(bfhi(q.w), xb.w, racc[r]);
                }
            }
            #pragma unroll
            for (int r = 0; r < ROWS; r++) {
                #pragma unroll
                for (int m = 1; m < 16; m <<= 1) racc[r] += __shfl_xor(racc[r], m, 64);
            }
            if (kl == 0) {
                #pragma unroll
                for (int r = 0; r < ROWS; r++) ys[r * 512 + o] = racc[r] + bc21[o];
            }
        }
        __syncthreads();
        // ===== P5: LN1 =====
        if (w < ROWS) {
            const int base = w * 512 + lane * 8;
            float v[8];
            *(float4*)&v[0] = *(const float4*)(ys + base);
            *(float4*)&v[4] = *(const float4*)(ys + base + 4);
            float sum = 0.f, ssq = 0.f;
            #pragma unroll
            for (int j = 0; j < 8; j++) { sum += v[j]; ssq += v[j] * v[j]; }
            #pragma unroll
            for (int m = 1; m < 64; m <<= 1) {
                sum += __shfl_xor(sum, m, 64);
                ssq += __shfl_xor(ssq, m, 64);
            }
            const float mu = sum * (1.f / 512.f);
            const float rstd = rsqrtf(ssq * (1.f / 512.f) - mu * mu + 1e-5f);
            #pragma unroll
            for (int j = 0; j < 8; j++) {
                const int o = lane * 8 + j;
                ys[base + j] = (v[j] - mu) * rstd * lg1[o] + lb1[o];
            }
        }
        __syncthreads();
        // ===== P6: comb2 -> c2s  (Wcomb2 bf16) =====
        for (int i = 0; i < 8; i++) {
            const int o = i * 64 + w * 4 + og;
            float racc[ROWS] = {0.f, 0.f, 0.f, 0.f};
            const uint4* wq = (const uint4*)(Wbcb2 + (size_t)o * 512);
            #pragma unroll
            for (int seg = 0; seg < 4; seg++) {
                uint4 q = wq[seg * 16 + kl];
                const int k = seg * 128 + kl * 8;
                #pragma unroll
                for (int r = 0; r < ROWS; r++) {
                    float4 xa = *(const float4*)(ys + r * 512 + k);
                    float4 xb = *(const float4*)(ys + r * 512 + k + 4);
                    racc[r] = fmaf(bflo(q.x), xa.x, racc[r]);
                    racc[r] = fmaf(bfhi(q.x), xa.y, racc[r]);
                    racc[r] = fmaf(bflo(q.y), xa.z, racc[r]);
                    racc[r] = fmaf(bfhi(q.y), xa.w, racc[r]);
                    racc[r] = fmaf(bflo(q.z), xb.x, racc[r]);
                    racc[r] = fmaf(bfhi(q.z), xb.y, racc[r]);
                    racc[r] = fmaf(bflo(q.w), xb.z, racc[r]);
                    racc[r] = fmaf(bfhi(q.w), xb.w, racc[r]);
                }
            }
            #pragma unroll
            for (int r = 0; r < ROWS; r++) {
                #pragma unroll
                for (int m = 1; m < 16; m <<= 1) racc[r] += __shfl_xor(racc[r], m, 64);
            }
            if (kl == 0) {
                #pragma unroll
                for (int r = 0; r < ROWS; r++) c2s[r * 512 + o] = racc[r] + beff[o];
            }
        }
        __syncthreads();
        // ===== P7: GRU2 dots -> gbuf  (Whh2 f32, Wih2 bf16) =====
        for (int i = 0; i < 24; i++) {
            const int o = i * 64 + w * 4 + og;
            float rH[ROWS] = {0.f, 0.f, 0.f, 0.f};
            float rI[ROWS] = {0.f, 0.f, 0.f, 0.f};
            const float* wh = Whh2 + (size_t)o * 512;
            const uint4* wqi = (const uint4*)(Wbih2 + (size_t)o * 512);
            #pragma unroll
            for (int seg = 0; seg < 4; seg++) {
                const int k = seg * 128 + kl * 8;
                float4 wa = *(const float4*)(wh + k);
                float4 wb = *(const float4*)(wh + k + 4);
                uint4 qi = wqi[seg * 16 + kl];
                #pragma unroll
                for (int r = 0; r < ROWS; r++) {
                    float4 ha = *(const float4*)(h2s + r * 512 + k);
                    float4 hb = *(const float4*)(h2s + r * 512 + k + 4);
                    float4 ca = *(const float4*)(c2s + r * 512 + k);
                    float4 cb = *(const float4*)(c2s + r * 512 + k + 4);
                    rH[r] = fmaf(wa.x, ha.x, rH[r]);
                    rH[r] = fmaf(wa.y, ha.y, rH[r]);
                    rH[r] = fmaf(wa.z, ha.z, rH[r]);
                    rH[r] = fmaf(wa.w, ha.w, rH[r]);
                    rH[r] = fmaf(wb.x, hb.x, rH[r]);
                    rH[r] = fmaf(wb.y, hb.y, rH[r]);
                    rH[r] = fmaf(wb.z, hb.z, rH[r]);
                    rH[r] = fmaf(wb.w, hb.w, rH[r]);
                    rI[r] = fmaf(bflo(qi.x), ca.x, rI[r]);
                    rI[r] = fmaf(bfhi(qi.x), ca.y, rI[r]);
                    rI[r] = fmaf(bflo(qi.y), ca.z, rI[r]);
                    rI[r] = fmaf(bfhi(qi.y), ca.w, rI[r]);
                    rI[r] = fmaf(bflo(qi.z), cb.x, rI[r]);
                    rI[r] = fmaf(bfhi(qi.z), cb.y, rI[r]);
                    rI[r] = fmaf(bflo(qi.w), cb.z, rI[r]);
                    rI[r] = fmaf(bfhi(qi.w), cb.w, rI[r]);
                }
            }
            #pragma unroll
            for (int r = 0; r < ROWS; r++) {
                #pragma unroll
                for (int m = 1; m < 16; m <<= 1) {
                    rH[r] += __shfl_xor(rH[r], m, 64);
                    rI[r] += __shfl_xor(rI[r], m, 64);
                }
            }
            if (kl == 0) {
                if (o < 1024) {
                    #pragma unroll
                    for (int r = 0; r < ROWS; r++) gbuf[o * ROWS + r] = rH[r] + rI[r];
                } else {
                    #pragma unroll
                    for (int r = 0; r < ROWS; r++) {
                        gbuf[o * ROWS + r] = rH[r];
                        gbuf[(512 + o) * ROWS + r] = rI[r];
                    }
                }
            }
        }
        __syncthreads();
        // ===== P8: gates2 -> h2s =====
        for (int c = tid; c < ROWS * 512; c += NT) {
            const int r = c & (ROWS - 1), h = c >> 2;
            const float m = mrow[r];
            const int cc = r * 512 + h;
            const float hold = h2s[cc];
            float xr = gbuf[h * ROWS + r] + bih2[h] + bhh2[h];
            float xz = gbuf[(512 + h) * ROWS + r] + bih2[512 + h] + bhh2[512 + h];
            float hn = gbuf[(1024 + h) * ROWS + r] + bhh2[1024 + h];
            float xn = gbuf[(1536 + h) * ROWS + r] + bih2[1024 + h];
            float rg = sigmoidf_(xr);
            float zg = sigmoidf_(xz);
            float ng = tanhf_(xn + rg * hn);
            h2s[cc] = ((1.f - zg) * ng + zg * hold) * m + hold * (1.f - m);
        }
        __syncthreads();
        // ===== P9: B2 out2 -> ys  (Wc22 f32) =====
        for (int i = 0; i < 8; i++) {
            const int o = i * 64 + w * 4 + og;
            float racc[ROWS] = {0.f, 0.f, 0.f, 0.f};
            const float* wr = Wc22 + (size_t)o * 1024;
            #pragma unroll
            for (int seg = 0; seg < 4; seg++) {
                const int k = seg * 128 + kl * 8;
                float4 wc1 = *(const float4*)(wr + k);
                float4 wc2 = *(const float4*)(wr + k + 4);
                float4 wh1 = *(const float4*)(wr + 512 + k);
                float4 wh2 = *(const float4*)(wr + 512 + k + 4);
                #pragma unroll
                for (int r = 0; r < ROWS; r++) {
                    float4 ca = *(const float4*)(c2s + r * 512 + k);
                    float4 cb = *(const float4*)(c2s + r * 512 + k + 4);
                    float4 ha = *(const float4*)(h2s + r * 512 + k);
                    float4 hb = *(const float4*)(h2s + r * 512 + k + 4);
                    racc[r] = fmaf(wc1.x, ca.x, racc[r]);
                    racc[r] = fmaf(wc1.y, ca.y, racc[r]);
                    racc[r] = fmaf(wc1.z, ca.z, racc[r]);
                    racc[r] = fmaf(wc1.w, ca.w, racc[r]);
                    racc[r] = fmaf(wc2.x, cb.x, racc[r]);
                    racc[r] = fmaf(wc2.y, cb.y, racc[r]);
                    racc[r] = fmaf(wc2.z, cb.z, racc[r]);
                    racc[r] = fmaf(wc2.w, cb.w, racc[r]);
                    racc[r] = fmaf(wh1.x, ha.x, racc[r]);
                    racc[r] = fmaf(wh1.y, ha.y, racc[r]);
                    racc[r] = fmaf(wh1.z, ha.z, racc[r]);
                    racc[r] = fmaf(wh1.w, ha.w, racc[r]);
                    racc[r] = fmaf(wh2.x, hb.x, racc[r]);
                    racc[r] = fmaf(wh2.y, hb.y, racc[r]);
                    racc[r] = fmaf(wh2.z, hb.z, racc[r]);
                    racc[r] = fmaf(wh2.w, hb.w, racc[r]);
                }
            }
            #pragma unroll
            for (int r = 0; r < ROWS; r++) {
                #pragma unroll
                for (int m = 1; m < 16; m <<= 1) racc[r] += __shfl_xor(racc[r], m, 64);
            }
            if (kl == 0) {
                #pragma unroll
                for (int r = 0; r < ROWS; r++) ys[r * 512 + o] = racc[r] + bc22[o];
            }
        }
        __syncthreads();
        // ===== P10: LN2 =====
        if (w < ROWS) {
            const int base = w * 512 + lane * 8;
            float v[8];
            *(float4*)&v[0] = *(const float4*)(ys + base);
            *(float4*)&v[4] = *(const float4*)(ys + base + 4);
            float sum = 0.f, ssq = 0.f;
            #pragma unroll
            for (int j = 0; j < 8; j++) { sum += v[j]; ssq += v[j] * v[j]; }
            #pragma unroll
            for (int m = 1; m < 64; m <<= 1) {
                sum += __shfl_xor(sum, m, 64);
                ssq += __shfl_xor(ssq, m, 64);
            }
            const float mu = sum * (1.f / 512.f);
            const float rstd = rsqrtf(ssq * (1.f / 512.f) - mu * mu + 1e-5f);
            #pragma unroll
            for (int j = 0; j < 8; j++) {
                const int o = lane * 8 + j;
                ys[base + j] = (v[j] - mu) * rstd * lg2[o] + lb2[o];
            }
        }
        __syncthreads();
        // ===== P11: head partials (waves 0..7) =====
        if (w < 8) {
            float p[ROWS];
            const float* wp = Wnn1 + w * 512 + lane * 8;
            float4 wa = *(const float4*)wp;
            float4 wb = *(const float4*)(wp + 4);
            #pragma unroll
            for (int r = 0; r < ROWS; r++) {
                const float* yp = ys + r * 512 + lane * 8;
                float4 ya = *(const float4*)yp;
                float4 yb = *(const float4*)(yp + 4);
                p[r] = ya.x * wa.x + ya.y * wa.y + ya.z * wa.z + ya.w * wa.w
                     + yb.x * wb.x + yb.y * wb.y + yb.z * wb.z + yb.w * wb.w;
            }
            #pragma unroll
            for (int m = 1; m < 64; m <<= 1) {
                #pragma unroll
                for (int r = 0; r < ROWS; r++) p[r] += __shfl_xor(p[r], m, 64);
            }
            if (lane == 0) {
                #pragma unroll
                for (int r = 0; r < ROWS; r++)
                    xm[w * ROWS + r] = fmaxf(p[r] + bnn1[w], 0.f);
            }
        }
        __syncthreads();
        // ===== P12: LN8 + final projection -> out[t] =====
        if (tid < ROWS) {
            const int r = tid;
            float tv[8], m8 = 0.f;
            #pragma unroll
            for (int o8 = 0; o8 < 8; o8++) { tv[o8] = xm[o8 * ROWS + r]; m8 += tv[o8]; }
            m8 *= 0.125f;
            float var = 0.f;
            #pragma unroll
            for (int o8 = 0; o8 < 8; o8++) { float d = tv[o8] - m8; var += d * d; }
            var *= 0.125f;
            const float rstd8 = rsqrtf(var + 1e-5f);
            float o0v = bnn2[0], o1v = bnn2[1];
            #pragma unroll
            for (int o8 = 0; o8 < 8; o8++) {
                float v = (tv[o8] - m8) * rstd8 * g3[o8] + b3v[o8];
                o0v += v * Wnn2[o8];
                o1v += v * Wnn2[8 + o8];
            }
            float* op = out + ((size_t)t * B_ + row0 + r) * 2;
            op[0] = o0v;
            op[1] = o1v;
        }
        __syncthreads();
    }
}

extern "C" void kernel_launch(void* const* d_in, const int* in_sizes, int n_in,
                              void* d_out, int out_size, void* d_ws, size_t ws_size,
                              hipStream_t stream) {
    const float* X      = (const float*)d_in[0];
    const float* M      = (const float*)d_in[1];
    const float* mask   = (const float*)d_in[2];
    const float* Wi2h   = (const float*)d_in[3];
    const float* bi2h   = (const float*)d_in[4];
    const float* Wcomb1 = (const float*)d_in[5];
    const float* bcomb1 = (const float*)d_in[6];
    const float* Wih1   = (const float*)d_in[7];
    const float* Whh1   = (const float*)d_in[8];
    const float* bih1   = (const float*)d_in[9];
    const float* bhh1   = (const float*)d_in[10];
    const float* Wc21   = (const float*)d_in[11];
    const float* bc21   = (const float*)d_in[12];
    const float* Wcomb2 = (const float*)d_in[13];
    const float* bcomb2 = (const float*)d_in[14];
    const float* Wih2   = (const float*)d_in[15];
    const float* Whh2   = (const float*)d_in[16];
    const float* bih2   = (const float*)d_in[17];
    const float* bhh2   = (const float*)d_in[18];
    const float* Wc22   = (const float*)d_in[19];
    const float* bc22   = (const float*)d_in[20];
    const float* g1     = (const float*)d_in[21];
    const float* b1     = (const float*)d_in[22];
    const float* g2     = (const float*)d_in[23];
    const float* b2     = (const float*)d_in[24];
    const float* g3     = (const float*)d_in[25];
    const float* b3     = (const float*)d_in[26];
    const float* Wnn1   = (const float*)d_in[27];
    const float* bnn1   = (const float*)d_in[28];
    const float* Wnn2   = (const float*)d_in[29];
    const float* bnn2   = (const float*)d_in[30];
    float* out = (float*)d_out;

    // ws layout: ctr(1KB) | beff(2KB) | pad | bf16 weights (~2.9MB)
    const size_t OFF_W = 4096;
    const size_t N_IH1 = 1536 * 64;
    const size_t N_C21 = 512 * 576;
    const size_t N_CB2 = 512 * 512;
    const size_t N_IH2 = 1536 * 512;
    const size_t NEED = OFF_W + 2 * (N_IH1 + N_C21 + N_CB2 + N_IH2) + 4096;
    if (ws_size < NEED) {
        float v = 1.0e4f + (float)(ws_size >> 20);
        k_sentinel<<<(out_size + 255) / 256, 256, 0, stream>>>(out, out_size, v);
        return;
    }
    char* ws = (char*)d_ws;
    u32* ctr   = (u32*)ws;
    float* beff = (float*)(ws + 1024);
    u16* p = (u16*)(ws + OFF_W);
    u16* wb_ih1 = p; p += N_IH1;
    u16* wb_c21 = p; p += N_C21;
    u16* wb_cb2 = p; p += N_CB2;
    u16* wb_ih2 = p; p += N_IH2;

    k_zero<<<1, 256, 0, stream>>>(ctr, 256);
    k_beff<<<2, 256, 0, stream>>>(Wcomb2, bcomb2, beff);
    k_pack<<<(int)(N_IH1 / 256), 256, 0, stream>>>(Wih1, wb_ih1, (int)N_IH1);
    k_pack<<<(int)(N_C21 / 256), 256, 0, stream>>>(Wc21, wb_c21, (int)N_C21);
    k_pack_cb2<<<(int)(N_CB2 / 256), 256, 0, stream>>>(Wcomb2, wb_cb2);
    k_pack<<<(int)(N_IH2 / 256), 256, 0, stream>>>(Wih2, wb_ih2, (int)N_IH2);

    k_scan_b<<<NB, NT, 0, stream>>>(
        X, M, mask, Wi2h, bi2h, Wcomb1, bcomb1,
        wb_ih1, Whh1, bih1, bhh1,
        wb_c21, bc21, g1, b1,
        wb_cb2, beff,
        wb_ih2, Whh2, bih2, bhh2,
        Wc22, bc22, g2, b2,
        Wnn1, bnn1, g3, b3, Wnn2, bnn2, ctr, out);
}

// Round 10
// 180161.145 us; speedup vs baseline: 1.6061x; 1.6061x over previous
//
#include <hip/hip_runtime.h>
#include <hip/hip_bf16.h>

typedef unsigned short u16;
typedef unsigned int   u32;

#define S_   256
#define B_   512
#define I_   70
#define ROWS 4
#define NB   (B_ / ROWS)   // 128 blocks
#define NT   1024          // 16 waves
#define NBAR 5             // pacing barriers per step

// ---- bf16 helpers ----
__device__ __forceinline__ float bflo(u32 u) {
    return __uint_as_float(u << 16);
}
__device__ __forceinline__ float bfhi(u32 u) {
    return __uint_as_float(u & 0xffff0000u);
}
__device__ __forceinline__ u16 f2bf_u(float f) {
    __hip_bfloat16 h = __float2bfloat16(f);
    u16 r;
    __builtin_memcpy(&r, &h, 2);
    return r;
}
__device__ __forceinline__ float sigmoidf_(float x) {
    x = fminf(fmaxf(x, -30.f), 30.f);
    return 1.f / (1.f + __expf(-x));
}
__device__ __forceinline__ float tanhf_(float x) {
    x = fminf(fmaxf(x, -15.f), 15.f);
    float e = __expf(2.f * x);
    return (e - 1.f) / (e + 1.f);
}

// ---- phase-convoy pacing barrier: alignment only, no data exchange ----
__device__ __forceinline__ void pace(u32* __restrict__ ctr, int idx) {
    __syncthreads();
    if (threadIdx.x == 0) {
        __hip_atomic_fetch_add(&ctr[idx], 1u, __ATOMIC_RELAXED,
                               __HIP_MEMORY_SCOPE_AGENT);
        while (__hip_atomic_load(&ctr[idx], __ATOMIC_RELAXED,
                                 __HIP_MEMORY_SCOPE_AGENT) < (u32)NB)
            __builtin_amdgcn_s_sleep(2);
    }
    __syncthreads();
}

// ---- diagnostic sentinel ----
__global__ __launch_bounds__(256)
void k_sentinel(float* __restrict__ out, int n, float v) {
    int i = blockIdx.x * 256 + threadIdx.x;
    if (i < n) out[i] = v;
}

// ---- zero the pacing counters ----
__global__ __launch_bounds__(256)
void k_zero(u32* __restrict__ p, int n) {
    int i = blockIdx.x * 256 + threadIdx.x;
    if (i < n) p[i] = 0u;
}

// ---- pack f32 -> bf16 ----
__global__ __launch_bounds__(256)
void k_pack(const float* __restrict__ src, u16* __restrict__ dst, int n) {
    int i = blockIdx.x * 256 + threadIdx.x;
    if (i < n) dst[i] = f2bf_u(src[i]);
}

// ---- pack first 512 cols of Wcomb2 [512][1024] -> bf16 [512][512] ----
__global__ __launch_bounds__(256)
void k_pack_cb2(const float* __restrict__ src, u16* __restrict__ dst) {
    int i = blockIdx.x * 256 + threadIdx.x;   // 512*512
    int e = i >> 9, k = i & 511;
    dst[i] = f2bf_u(src[(size_t)e * 1024 + k]);
}

// ---- beff[e] = bcomb2[e] + sum_h Wcomb2[e][512+h]  (M==ones fold) ----
__global__ __launch_bounds__(256)
void k_beff(const float* __restrict__ Wcomb2, const float* __restrict__ bcomb2,
            float* __restrict__ beff) {
    int e = blockIdx.x * 256 + threadIdx.x;
    if (e >= 512) return;
    float s = bcomb2[e];
    const float* wp = Wcomb2 + (size_t)e * 1024 + 512;
    for (int k = 0; k < 512; k++) s += wp[k];
    beff[e] = s;
}

// ====== persistent batch-partitioned scan, phase-convoyed weight stream ======
// f32:  Whh1, Whh2, Wc22.  bf16: Wih1, Wc21, Wcomb2[:, :512], Wih2.
// 5 pacing barriers/step fence weight segments that each fit a 4MB XCD L2:
//  b0 {Wcomb1,Whh1,Wih1}=3.4MB  b1 {Wc21,Wcomb2}=1.1MB  b2 {Whh2}=3MB
//  b3 {Wih2}=1.5MB  b4 {Wc22,Wnn1}=2.1MB
__global__ __launch_bounds__(NT, 1)
void k_scan_b(const float* __restrict__ X, const float* __restrict__ M,
              const float* __restrict__ mask,
              const float* __restrict__ Wi2h, const float* __restrict__ bi2h,
              const float* __restrict__ Wcomb1, const float* __restrict__ bcomb1,
              const u16* __restrict__ Wbih1, const float* __restrict__ Whh1,
              const float* __restrict__ bih1, const float* __restrict__ bhh1,
              const u16* __restrict__ Wbc21, const float* __restrict__ bc21,
              const float* __restrict__ lg1, const float* __restrict__ lb1,
              const u16* __restrict__ Wbcb2, const float* __restrict__ beff,
              const u16* __restrict__ Wbih2, const float* __restrict__ Whh2,
              const float* __restrict__ bih2, const float* __restrict__ bhh2,
              const float* __restrict__ Wc22, const float* __restrict__ bc22,
              const float* __restrict__ lg2, const float* __restrict__ lb2,
              const float* __restrict__ Wnn1, const float* __restrict__ bnn1,
              const float* __restrict__ g3, const float* __restrict__ b3v,
              const float* __restrict__ Wnn2, const float* __restrict__ bnn2,
              u32* __restrict__ ctr, float* __restrict__ out) {
    __shared__ float h1s[ROWS * 512];
    __shared__ float h2s[ROWS * 512];
    __shared__ float c2s[ROWS * 512];
    __shared__ float gbuf[2048 * ROWS];    // ys aliases gbuf[0:2048)
    __shared__ float c1s[ROWS * 64];
    __shared__ float xm[ROWS * 128];
    float* ys = gbuf;

    const int tid  = threadIdx.x;
    const int w    = tid >> 6;
    const int lane = tid & 63;
    const int og   = lane >> 4;
    const int kl   = lane & 15;
    const int row0 = blockIdx.x * ROWS;

    // ---- h0 init (both layers) ----
    for (int c = tid; c < ROWS * 512; c += NT) {
        int r = c >> 9, h = c & 511;
        const float* xp = X + (size_t)(row0 + r) * I_ + 64;
        const float* wp = Wi2h + h * 6;
        float s = bi2h[h];
        #pragma unroll
        for (int j = 0; j < 6; j++) s = fmaf(xp[j], wp[j], s);
        h1s[c] = s;
        h2s[c] = s;
    }
    __syncthreads();

    for (int t = 0; t < S_; t++) {
        const float* mrow = mask + (size_t)t * B_ + row0;

        // ======== convoy point b0: {Wcomb1, Whh1, Wih1} ========
        pace(ctr, t * NBAR + 0);

        // ===== P0: stage X/M rows -> xm =====
        for (int c = tid; c < ROWS * 128; c += NT) {
            int r = c >> 7, k = c & 127;
            size_t rg = (size_t)t * B_ + row0 + r;
            xm[c] = (k < 64) ? X[rg * I_ + k] : M[rg * I_ + (k - 64)];
        }
        __syncthreads();

        // ===== P1: comb1 -> c1s =====
        {
            const int o = w * 4 + og;
            float racc[ROWS] = {0.f, 0.f, 0.f, 0.f};
            const float* wr = Wcomb1 + o * 128;
            #pragma unroll
            for (int seg = 0; seg < 2; seg++) {
                const int k = seg * 64 + kl * 4;
                float4 wv = *(const float4*)(wr + k);
                #pragma unroll
                for (int r = 0; r < ROWS; r++) {
                    float4 xv = *(const float4*)(xm + r * 128 + k);
                    racc[r] = fmaf(wv.x, xv.x, racc[r]);
                    racc[r] = fmaf(wv.y, xv.y, racc[r]);
                    racc[r] = fmaf(wv.z, xv.z, racc[r]);
                    racc[r] = fmaf(wv.w, xv.w, racc[r]);
                }
            }
            #pragma unroll
            for (int r = 0; r < ROWS; r++) {
                #pragma unroll
                for (int m = 1; m < 16; m <<= 1) racc[r] += __shfl_xor(racc[r], m, 64);
            }
            if (kl == 0) {
                #pragma unroll
                for (int r = 0; r < ROWS; r++) c1s[r * 64 + o] = racc[r] + bcomb1[o];
            }
        }
        __syncthreads();

        // ===== P2: GRU1 dots -> gbuf  (Whh1 f32, Wih1 bf16) =====
        for (int i = 0; i < 24; i++) {
            const int o = i * 64 + w * 4 + og;
            float rH[ROWS] = {0.f, 0.f, 0.f, 0.f};
            float rI[ROWS] = {0.f, 0.f, 0.f, 0.f};
            const float* wh = Whh1 + (size_t)o * 512;
            #pragma unroll
            for (int seg = 0; seg < 4; seg++) {
                const int k = seg * 128 + kl * 8;
                float4 wa = *(const float4*)(wh + k);
                float4 wb = *(const float4*)(wh + k + 4);
                #pragma unroll
                for (int r = 0; r < ROWS; r++) {
                    float4 xa = *(const float4*)(h1s + r * 512 + k);
                    float4 xb = *(const float4*)(h1s + r * 512 + k + 4);
                    rH[r] = fmaf(wa.x, xa.x, rH[r]);
                    rH[r] = fmaf(wa.y, xa.y, rH[r]);
                    rH[r] = fmaf(wa.z, xa.z, rH[r]);
                    rH[r] = fmaf(wa.w, xa.w, rH[r]);
                    rH[r] = fmaf(wb.x, xb.x, rH[r]);
                    rH[r] = fmaf(wb.y, xb.y, rH[r]);
                    rH[r] = fmaf(wb.z, xb.z, rH[r]);
                    rH[r] = fmaf(wb.w, xb.w, rH[r]);
                }
            }
            {
                uint2 q = ((const uint2*)(Wbih1 + (size_t)o * 64))[kl];
                const int k = kl * 4;
                #pragma unroll
                for (int r = 0; r < ROWS; r++) {
                    float4 xa = *(const float4*)(c1s + r * 64 + k);
                    rI[r] = fmaf(bflo(q.x), xa.x, rI[r]);
                    rI[r] = fmaf(bfhi(q.x), xa.y, rI[r]);
                    rI[r] = fmaf(bflo(q.y), xa.z, rI[r]);
                    rI[r] = fmaf(bfhi(q.y), xa.w, rI[r]);
                }
            }
            #pragma unroll
            for (int r = 0; r < ROWS; r++) {
                #pragma unroll
                for (int m = 1; m < 16; m <<= 1) {
                    rH[r] += __shfl_xor(rH[r], m, 64);
                    rI[r] += __shfl_xor(rI[r], m, 64);
                }
            }
            if (kl == 0) {
                if (o < 1024) {
                    #pragma unroll
                    for (int r = 0; r < ROWS; r++) gbuf[o * ROWS + r] = rH[r] + rI[r];
                } else {
                    #pragma unroll
                    for (int r = 0; r < ROWS; r++) {
                        gbuf[o * ROWS + r] = rH[r];
                        gbuf[(512 + o) * ROWS + r] = rI[r];
                    }
                }
            }
        }
        __syncthreads();
        // ===== P3: gates1 -> h1s =====
        for (int c = tid; c < ROWS * 512; c += NT) {
            const int r = c & (ROWS - 1), h = c >> 2;
            const float m = mrow[r];
            const int cc = r * 512 + h;
            const float hold = h1s[cc];
            float xr = gbuf[h * ROWS + r] + bih1[h] + bhh1[h];
            float xz = gbuf[(512 + h) * ROWS + r] + bih1[512 + h] + bhh1[512 + h];
            float hn = gbuf[(1024 + h) * ROWS + r] + bhh1[1024 + h];
            float xn = gbuf[(1536 + h) * ROWS + r] + bih1[1024 + h];
            float rg = sigmoidf_(xr);
            float zg = sigmoidf_(xz);
            float ng = tanhf_(xn + rg * hn);
            h1s[cc] = ((1.f - zg) * ng + zg * hold) * m + hold * (1.f - m);
        }

        // ======== convoy point b1: {Wc21, Wcomb2} ========
        pace(ctr, t * NBAR + 1);

        // ===== P4: B1a out1 -> ys  (Wc21 bf16) =====
        for (int i = 0; i < 8; i++) {
            const int o = i * 64 + w * 4 + og;
            float racc[ROWS] = {0.f, 0.f, 0.f, 0.f};
            const u16* wr = Wbc21 + (size_t)o * 576;
            {
                uint2 q = ((const uint2*)wr)[kl];
                const int k = kl * 4;
                #pragma unroll
                for (int r = 0; r < ROWS; r++) {
                    float4 xa = *(const float4*)(c1s + r * 64 + k);
                    racc[r] = fmaf(bflo(q.x), xa.x, racc[r]);
                    racc[r] = fmaf(bfhi(q.x), xa.y, racc[r]);
                    racc[r] = fmaf(bflo(q.y), xa.z, racc[r]);
                    racc[r] = fmaf(bfhi(q.y), xa.w, racc[r]);
                }
            }
            const uint4* wq = (const uint4*)(wr + 64);
            #pragma unroll
            for (int seg = 0; seg < 4; seg++) {
                uint4 q = wq[seg * 16 + kl];
                const int k = seg * 128 + kl * 8;
                #pragma unroll
                for (int r = 0; r < ROWS; r++) {
                    float4 xa = *(const float4*)(h1s + r * 512 + k);
                    float4 xb = *(const float4*)(h1s + r * 512 + k + 4);
                    racc[r] = fmaf(bflo(q.x), xa.x, racc[r]);
                    racc[r] = fmaf(bfhi(q.x), xa.y, racc[r]);
                    racc[r] = fmaf(bflo(q.y), xa.z, racc[r]);
                    racc[r] = fmaf(bfhi(q.y), xa.w, racc[r]);
                    racc[r] = fmaf(bflo(q.z), xb.x, racc[r]);
                    racc[r] = fmaf(bfhi(q.z), xb.y, racc[r]);
                    racc[r] = fmaf(bflo(q.w), xb.z, racc[r]);
                    racc[r] = fmaf(bfhi(q.w), xb.w, racc[r]);
                }
            }
            #pragma unroll
            for (int r = 0; r < ROWS; r++) {
                #pragma unroll
                for (int m = 1; m < 16; m <<= 1) racc[r] += __shfl_xor(racc[r], m, 64);
            }
            if (kl == 0) {
                #pragma unroll
                for (int r = 0; r < ROWS; r++) ys[r * 512 + o] = racc[r] + bc21[o];
            }
        }
        __syncthreads();
        // ===== P5: LN1 =====
        if (w < ROWS) {
            const int base = w * 512 + lane * 8;
            float v[8];
            *(float4*)&v[0] = *(const float4*)(ys + base);
            *(float4*)&v[4] = *(const float4*)(ys + base + 4);
            float sum = 0.f, ssq = 0.f;
            #pragma unroll
            for (int j = 0; j < 8; j++) { sum += v[j]; ssq += v[j] * v[j]; }
            #pragma unroll
            for (int m = 1; m < 64; m <<= 1) {
                sum += __shfl_xor(sum, m, 64);
                ssq += __shfl_xor(ssq, m, 64);
            }
            const float mu = sum * (1.f / 512.f);
            const float rstd = rsqrtf(ssq * (1.f / 512.f) - mu * mu + 1e-5f);
            #pragma unroll
            for (int j = 0; j < 8; j++) {
                const int o = lane * 8 + j;
                ys[base + j] = (v[j] - mu) * rstd * lg1[o] + lb1[o];
            }
        }
        __syncthreads();
        // ===== P6: comb2 -> c2s  (Wcomb2 bf16) =====
        for (int i = 0; i < 8; i++) {
            const int o = i * 64 + w * 4 + og;
            float racc[ROWS] = {0.f, 0.f, 0.f, 0.f};
            const uint4* wq = (const uint4*)(Wbcb2 + (size_t)o * 512);
            #pragma unroll
            for (int seg = 0; seg < 4; seg++) {
                uint4 q = wq[seg * 16 + kl];
                const int k = seg * 128 + kl * 8;
                #pragma unroll
                for (int r = 0; r < ROWS; r++) {
                    float4 xa = *(const float4*)(ys + r * 512 + k);
                    float4 xb = *(const float4*)(ys + r * 512 + k + 4);
                    racc[r] = fmaf(bflo(q.x), xa.x, racc[r]);
                    racc[r] = fmaf(bfhi(q.x), xa.y, racc[r]);
                    racc[r] = fmaf(bflo(q.y), xa.z, racc[r]);
                    racc[r] = fmaf(bfhi(q.y), xa.w, racc[r]);
                    racc[r] = fmaf(bflo(q.z), xb.x, racc[r]);
                    racc[r] = fmaf(bfhi(q.z), xb.y, racc[r]);
                    racc[r] = fmaf(bflo(q.w), xb.z, racc[r]);
                    racc[r] = fmaf(bfhi(q.w), xb.w, racc[r]);
                }
            }
            #pragma unroll
            for (int r = 0; r < ROWS; r++) {
                #pragma unroll
                for (int m = 1; m < 16; m <<= 1) racc[r] += __shfl_xor(racc[r], m, 64);
            }
            if (kl == 0) {
                #pragma unroll
                for (int r = 0; r < ROWS; r++) c2s[r * 512 + o] = racc[r] + beff[o];
            }
        }

        // ======== convoy point b2: {Whh2} ========
        pace(ctr, t * NBAR + 2);

        // ===== P7a: GRU2 hidden dots (Whh2 f32) -> gbuf =====
        for (int i = 0; i < 24; i++) {
            const int o = i * 64 + w * 4 + og;
            float rH[ROWS] = {0.f, 0.f, 0.f, 0.f};
            const float* wh = Whh2 + (size_t)o * 512;
            #pragma unroll
            for (int seg = 0; seg < 4; seg++) {
                const int k = seg * 128 + kl * 8;
                float4 wa = *(const float4*)(wh + k);
                float4 wb = *(const float4*)(wh + k + 4);
                #pragma unroll
                for (int r = 0; r < ROWS; r++) {
                    float4 ha = *(const float4*)(h2s + r * 512 + k);
                    float4 hb = *(const float4*)(h2s + r * 512 + k + 4);
                    rH[r] = fmaf(wa.x, ha.x, rH[r]);
                    rH[r] = fmaf(wa.y, ha.y, rH[r]);
                    rH[r] = fmaf(wa.z, ha.z, rH[r]);
                    rH[r] = fmaf(wa.w, ha.w, rH[r]);
                    rH[r] = fmaf(wb.x, hb.x, rH[r]);
                    rH[r] = fmaf(wb.y, hb.y, rH[r]);
                    rH[r] = fmaf(wb.z, hb.z, rH[r]);
                    rH[r] = fmaf(wb.w, hb.w, rH[r]);
                }
            }
            #pragma unroll
            for (int r = 0; r < ROWS; r++) {
                #pragma unroll
                for (int m = 1; m < 16; m <<= 1) rH[r] += __shfl_xor(rH[r], m, 64);
            }
            if (kl == 0) {
                #pragma unroll
                for (int r = 0; r < ROWS; r++) gbuf[o * ROWS + r] = rH[r];
            }
        }

        // ======== convoy point b3: {Wih2} ========
        pace(ctr, t * NBAR + 3);

        // ===== P7b: GRU2 input dots (Wih2 bf16) -> combine into gbuf =====
        for (int i = 0; i < 24; i++) {
            const int o = i * 64 + w * 4 + og;
            float rI[ROWS] = {0.f, 0.f, 0.f, 0.f};
            const uint4* wqi = (const uint4*)(Wbih2 + (size_t)o * 512);
            #pragma unroll
            for (int seg = 0; seg < 4; seg++) {
                uint4 qi = wqi[seg * 16 + kl];
                const int k = seg * 128 + kl * 8;
                #pragma unroll
                for (int r = 0; r < ROWS; r++) {
                    float4 ca = *(const float4*)(c2s + r * 512 + k);
                    float4 cb = *(const float4*)(c2s + r * 512 + k + 4);
                    rI[r] = fmaf(bflo(qi.x), ca.x, rI[r]);
                    rI[r] = fmaf(bfhi(qi.x), ca.y, rI[r]);
                    rI[r] = fmaf(bflo(qi.y), ca.z, rI[r]);
                    rI[r] = fmaf(bfhi(qi.y), ca.w, rI[r]);
                    rI[r] = fmaf(bflo(qi.z), cb.x, rI[r]);
                    rI[r] = fmaf(bfhi(qi.z), cb.y, rI[r]);
                    rI[r] = fmaf(bflo(qi.w), cb.z, rI[r]);
                    rI[r] = fmaf(bfhi(qi.w), cb.w, rI[r]);
                }
            }
            #pragma unroll
            for (int r = 0; r < ROWS; r++) {
                #pragma unroll
                for (int m = 1; m < 16; m <<= 1) rI[r] += __shfl_xor(rI[r], m, 64);
            }
            if (kl == 0) {
                if (o < 1024) {
                    #pragma unroll
                    for (int r = 0; r < ROWS; r++) gbuf[o * ROWS + r] += rI[r];
                } else {
                    #pragma unroll
                    for (int r = 0; r < ROWS; r++) gbuf[(512 + o) * ROWS + r] = rI[r];
                }
            }
        }
        __syncthreads();
        // ===== P8: gates2 -> h2s =====
        for (int c = tid; c < ROWS * 512; c += NT) {
            const int r = c & (ROWS - 1), h = c >> 2;
            const float m = mrow[r];
            const int cc = r * 512 + h;
            const float hold = h2s[cc];
            float xr = gbuf[h * ROWS + r] + bih2[h] + bhh2[h];
            float xz = gbuf[(512 + h) * ROWS + r] + bih2[512 + h] + bhh2[512 + h];
            float hn = gbuf[(1024 + h) * ROWS + r] + bhh2[1024 + h];
            float xn = gbuf[(1536 + h) * ROWS + r] + bih2[1024 + h];
            float rg = sigmoidf_(xr);
            float zg = sigmoidf_(xz);
            float ng = tanhf_(xn + rg * hn);
            h2s[cc] = ((1.f - zg) * ng + zg * hold) * m + hold * (1.f - m);
        }

        // ======== convoy point b4: {Wc22, Wnn1} ========
        pace(ctr, t * NBAR + 4);

        // ===== P9: B2 out2 -> ys  (Wc22 f32) =====
        for (int i = 0; i < 8; i++) {
            const int o = i * 64 + w * 4 + og;
            float racc[ROWS] = {0.f, 0.f, 0.f, 0.f};
            const float* wr = Wc22 + (size_t)o * 1024;
            #pragma unroll
            for (int seg = 0; seg < 4; seg++) {
                const int k = seg * 128 + kl * 8;
                float4 wc1 = *(const float4*)(wr + k);
                float4 wc2 = *(const float4*)(wr + k + 4);
                float4 wh1 = *(const float4*)(wr + 512 + k);
                float4 wh2 = *(const float4*)(wr + 512 + k + 4);
                #pragma unroll
                for (int r = 0; r < ROWS; r++) {
                    float4 ca = *(const float4*)(c2s + r * 512 + k);
                    float4 cb = *(const float4*)(c2s + r * 512 + k + 4);
                    float4 ha = *(const float4*)(h2s + r * 512 + k);
                    float4 hb = *(const float4*)(h2s + r * 512 + k + 4);
                    racc[r] = fmaf(wc1.x, ca.x, racc[r]);
                    racc[r] = fmaf(wc1.y, ca.y, racc[r]);
                    racc[r] = fmaf(wc1.z, ca.z, racc[r]);
                    racc[r] = fmaf(wc1.w, ca.w, racc[r]);
                    racc[r] = fmaf(wc2.x, cb.x, racc[r]);
                    racc[r] = fmaf(wc2.y, cb.y, racc[r]);
                    racc[r] = fmaf(wc2.z, cb.z, racc[r]);
                    racc[r] = fmaf(wc2.w, cb.w, racc[r]);
                    racc[r] = fmaf(wh1.x, ha.x, racc[r]);
                    racc[r] = fmaf(wh1.y, ha.y, racc[r]);
                    racc[r] = fmaf(wh1.z, ha.z, racc[r]);
                    racc[r] = fmaf(wh1.w, ha.w, racc[r]);
                    racc[r] = fmaf(wh2.x, hb.x, racc[r]);
                    racc[r] = fmaf(wh2.y, hb.y, racc[r]);
                    racc[r] = fmaf(wh2.z, hb.z, racc[r]);
                    racc[r] = fmaf(wh2.w, hb.w, racc[r]);
                }
            }
            #pragma unroll
            for (int r = 0; r < ROWS; r++) {
                #pragma unroll
                for (int m = 1; m < 16; m <<= 1) racc[r] += __shfl_xor(racc[r], m, 64);
            }
            if (kl == 0) {
                #pragma unroll
                for (int r = 0; r < ROWS; r++) ys[r * 512 + o] = racc[r] + bc22[o];
            }
        }
        __syncthreads();
        // ===== P10: LN2 =====
        if (w < ROWS) {
            const int base = w * 512 + lane * 8;
            float v[8];
            *(float4*)&v[0] = *(const float4*)(ys + base);
            *(float4*)&v[4] = *(const float4*)(ys + base + 4);
            float sum = 0.f, ssq = 0.f;
            #pragma unroll
            for (int j = 0; j < 8; j++) { sum += v[j]; ssq += v[j] * v[j]; }
            #pragma unroll
            for (int m = 1; m < 64; m <<= 1) {
                sum += __shfl_xor(sum, m, 64);
                ssq += __shfl_xor(ssq, m, 64);
            }
            const float mu = sum * (1.f / 512.f);
            const float rstd = rsqrtf(ssq * (1.f / 512.f) - mu * mu + 1e-5f);
            #pragma unroll
            for (int j = 0; j < 8; j++) {
                const int o = lane * 8 + j;
                ys[base + j] = (v[j] - mu) * rstd * lg2[o] + lb2[o];
            }
        }
        __syncthreads();
        // ===== P11: head partials (waves 0..7) =====
        if (w < 8) {
            float p[ROWS];
            const float* wp = Wnn1 + w * 512 + lane * 8;
            float4 wa = *(const float4*)wp;
            float4 wb = *(const float4*)(wp + 4);
            #pragma unroll
            for (int r = 0; r < ROWS; r++) {
                const float* yp = ys + r * 512 + lane * 8;
                float4 ya = *(const float4*)yp;
                float4 yb = *(const float4*)(yp + 4);
                p[r] = ya.x * wa.x + ya.y * wa.y + ya.z * wa.z + ya.w * wa.w
                     + yb.x * wb.x + yb.y * wb.y + yb.z * wb.z + yb.w * wb.w;
            }
            #pragma unroll
            for (int m = 1; m < 64; m <<= 1) {
                #pragma unroll
                for (int r = 0; r < ROWS; r++) p[r] += __shfl_xor(p[r], m, 64);
            }
            if (lane == 0) {
                #pragma unroll
                for (int r = 0; r < ROWS; r++)
                    xm[w * ROWS + r] = fmaxf(p[r] + bnn1[w], 0.f);
            }
        }
        __syncthreads();
        // ===== P12: LN8 + final projection -> out[t] =====
        if (tid < ROWS) {
            const int r = tid;
            float tv[8], m8 = 0.f;
            #pragma unroll
            for (int o8 = 0; o8 < 8; o8++) { tv[o8] = xm[o8 * ROWS + r]; m8 += tv[o8]; }
            m8 *= 0.125f;
            float var = 0.f;
            #pragma unroll
            for (int o8 = 0; o8 < 8; o8++) { float d = tv[o8] - m8; var += d * d; }
            var *= 0.125f;
            const float rstd8 = rsqrtf(var + 1e-5f);
            float o0v = bnn2[0], o1v = bnn2[1];
            #pragma unroll
            for (int o8 = 0; o8 < 8; o8++) {
                float v = (tv[o8] - m8) * rstd8 * g3[o8] + b3v[o8];
                o0v += v * Wnn2[o8];
                o1v += v * Wnn2[8 + o8];
            }
            float* op = out + ((size_t)t * B_ + row0 + r) * 2;
            op[0] = o0v;
            op[1] = o1v;
        }
        __syncthreads();
    }
}

extern "C" void kernel_launch(void* const* d_in, const int* in_sizes, int n_in,
                              void* d_out, int out_size, void* d_ws, size_t ws_size,
                              hipStream_t stream) {
    const float* X      = (const float*)d_in[0];
    const float* M      = (const float*)d_in[1];
    const float* mask   = (const float*)d_in[2];
    const float* Wi2h   = (const float*)d_in[3];
    const float* bi2h   = (const float*)d_in[4];
    const float* Wcomb1 = (const float*)d_in[5];
    const float* bcomb1 = (const float*)d_in[6];
    const float* Wih1   = (const float*)d_in[7];
    const float* Whh1   = (const float*)d_in[8];
    const float* bih1   = (const float*)d_in[9];
    const float* bhh1   = (const float*)d_in[10];
    const float* Wc21   = (const float*)d_in[11];
    const float* bc21   = (const float*)d_in[12];
    const float* Wcomb2 = (const float*)d_in[13];
    const float* bcomb2 = (const float*)d_in[14];
    const float* Wih2   = (const float*)d_in[15];
    const float* Whh2   = (const float*)d_in[16];
    const float* bih2   = (const float*)d_in[17];
    const float* bhh2   = (const float*)d_in[18];
    const float* Wc22   = (const float*)d_in[19];
    const float* bc22   = (const float*)d_in[20];
    const float* g1     = (const float*)d_in[21];
    const float* b1     = (const float*)d_in[22];
    const float* g2     = (const float*)d_in[23];
    const float* b2     = (const float*)d_in[24];
    const float* g3     = (const float*)d_in[25];
    const float* b3     = (const float*)d_in[26];
    const float* Wnn1   = (const float*)d_in[27];
    const float* bnn1   = (const float*)d_in[28];
    const float* Wnn2   = (const float*)d_in[29];
    const float* bnn2   = (const float*)d_in[30];
    float* out = (float*)d_out;

    // ws layout: ctr(8KB) | beff(2KB+pad) | bf16 weights (~2.9MB)
    const size_t OFF_W = 16384;
    const size_t N_IH1 = 1536 * 64;
    const size_t N_C21 = 512 * 576;
    const size_t N_CB2 = 512 * 512;
    const size_t N_IH2 = 1536 * 512;
    const size_t NEED = OFF_W + 2 * (N_IH1 + N_C21 + N_CB2 + N_IH2) + 4096;
    if (ws_size < NEED) {
        float v = 1.0e4f + (float)(ws_size >> 20);
        k_sentinel<<<(out_size + 255) / 256, 256, 0, stream>>>(out, out_size, v);
        return;
    }
    char* ws = (char*)d_ws;
    u32* ctr   = (u32*)ws;                  // 2048 counters (uses 1280)
    float* beff = (float*)(ws + 8192);
    u16* p = (u16*)(ws + OFF_W);
    u16* wb_ih1 = p; p += N_IH1;
    u16* wb_c21 = p; p += N_C21;
    u16* wb_cb2 = p; p += N_CB2;
    u16* wb_ih2 = p; p += N_IH2;

    k_zero<<<8, 256, 0, stream>>>(ctr, 2048);
    k_beff<<<2, 256, 0, stream>>>(Wcomb2, bcomb2, beff);
    k_pack<<<(int)(N_IH1 / 256), 256, 0, stream>>>(Wih1, wb_ih1, (int)N_IH1);
    k_pack<<<(int)(N_C21 / 256), 256, 0, stream>>>(Wc21, wb_c21, (int)N_C21);
    k_pack_cb2<<<(int)(N_CB2 / 256), 256, 0, stream>>>(Wcomb2, wb_cb2);
    k_pack<<<(int)(N_IH2 / 256), 256, 0, stream>>>(Wih2, wb_ih2, (int)N_IH2);

    k_scan_b<<<NB, NT, 0, stream>>>(
        X, M, mask, Wi2h, bi2h, Wcomb1, bcomb1,
        wb_ih1, Whh1, bih1, bhh1,
        wb_c21, bc21, g1, b1,
        wb_cb2, beff,
        wb_ih2, Whh2, bih2, bhh2,
        Wc22, bc22, g2, b2,
        Wnn1, bnn1, g3, b3, Wnn2, bnn2, ctr, out);
}